// Round 3
// baseline (188.712 us; speedup 1.0000x reference)
//
#include <hip/hip_runtime.h>

// ---------------------------------------------------------------------------
// ConfidenceBiasedCrossAttention: bf16-MFMA pipeline, round 3
//   B=2, Lq=1024, Lk=4096, C=1024, H=16, D=64
//   cvt weights / prep bias -> Q/K/V proj GEMMs -> attn (32x32 mfma, swapped
//   QK, in-register P, bias-in-MFMA, l-via-MFMA, defer-max, global_load_lds,
//   split-K x4) -> combine -> O GEMM
// ws layout (64.5 MB proven budget):
//   0M Wqb(2M) [ml 1M aliases after Q-proj] | 2M Wkb | 4M Wvb | 6M Wob |
//   8M qh(4M) | 12M kh(16M) | 28M vT(16M) | 44M Oh fp16(16M) | 60M ao(4M) |
//   64M kb(32KB)
// ---------------------------------------------------------------------------

typedef __attribute__((ext_vector_type(8))) __bf16 bf16x8;
typedef __attribute__((ext_vector_type(4))) float f32x4;
typedef __attribute__((ext_vector_type(16))) float f32x16;

#define LOG2E 1.44269504f

__device__ __forceinline__ unsigned short f2bf(float f) {
  union { float f; unsigned u; } v; v.f = f;
  unsigned r = v.u + 0x7fffu + ((v.u >> 16) & 1u);   // RNE
  return (unsigned short)(r >> 16);
}
__device__ __forceinline__ unsigned short f2h(float x) {
  _Float16 h = (_Float16)x;
  return __builtin_bit_cast(unsigned short, h);
}
__device__ __forceinline__ float h2f(unsigned short u) {
  return (float)__builtin_bit_cast(_Float16, u);
}

__device__ __forceinline__ f32x4 mfma16(bf16x8 a, bf16x8 b, f32x4 c) {
  return __builtin_amdgcn_mfma_f32_16x16x32_bf16(a, b, c, 0, 0, 0);
}
__device__ __forceinline__ f32x16 mfma32(bf16x8 a, bf16x8 b, f32x16 c) {
  return __builtin_amdgcn_mfma_f32_32x32x16_bf16(a, b, c, 0, 0, 0);
}

// pack two f32 -> u32 of 2 bf16 (v_cvt_pk_bf16_f32)
__device__ __forceinline__ unsigned pk2(float lo, float hi) {
  unsigned short a = __builtin_bit_cast(unsigned short, (__bf16)lo);
  unsigned short b = __builtin_bit_cast(unsigned short, (__bf16)hi);
  return (unsigned)a | ((unsigned)b << 16);
}

// async global->LDS, 16B per lane; LDS dest = wave-uniform base + lane*16
template <typename T>
__device__ __forceinline__ void gload16(const T* g, T* l) {
  __builtin_amdgcn_global_load_lds(
      (const __attribute__((address_space(1))) void*)g,
      (__attribute__((address_space(3))) void*)l, 16, 0, 0);
}

// ------------------------------ weight convert ------------------------------
struct Cvt4 {
  const float* src[4];
  unsigned short* dst[4];
};

__global__ __launch_bounds__(256) void cvt4_kernel(Cvt4 a, int n4) {
  const float4* s = (const float4*)a.src[blockIdx.y];
  unsigned short* d = a.dst[blockIdx.y];
  int stride = gridDim.x * blockDim.x;
  for (int i = blockIdx.x * blockDim.x + threadIdx.x; i < n4; i += stride) {
    float4 f = s[i];
    ushort4 u;
    u.x = f2bf(f.x); u.y = f2bf(f.y); u.z = f2bf(f.z); u.w = f2bf(f.w);
    ((ushort4*)d)[i] = u;
  }
}

// bias -> (bf16 hi, bf16 residual) pair in exp2 domain, packed u32
__global__ __launch_bounds__(256) void prep_kb(const float* __restrict__ Vb,
                                               unsigned* __restrict__ kb) {
  const int i = blockIdx.x * 256 + threadIdx.x;   // 8192
  const float x = Vb[i] * LOG2E;
  const unsigned short h = f2bf(x);
  union { unsigned u; float f; } hf; hf.u = (unsigned)h << 16;
  const unsigned short lo = f2bf(x - hf.f);
  kb[i] = (unsigned)h | ((unsigned)lo << 16);
}

// ------------------------------ projection GEMM -----------------------------
// out[m][n] = (sum_k A[m][k] * W[n][k] + bias[n]) * oscale
// MODE 0: out bf16, head-split  [b][h][l][64]   (Q / K projections)
// MODE 1: out bf16, transposed  vT[b][h][d][Lk]  (V projection; swapped mfma)
// MODE 2: out fp32, plain [M][N]                 (output projection)
template <int MODE, bool AF32>
__global__ __launch_bounds__(256) void gemm_bf16(
    const void* __restrict__ Ap, const unsigned short* __restrict__ W,
    const float* __restrict__ bias, void* __restrict__ outp,
    int M, int Llog2, float oscale) {
  constexpr int K = 1024, N = 1024;
  __shared__ unsigned short Alds[128][40];   // +8 pad
  __shared__ unsigned short Blds[128][40];

  const int tid = threadIdx.x;
  const int wid = tid >> 6, l = tid & 63;
  const int wr = wid >> 1, wc = wid & 1;
  const int m0 = blockIdx.x * 128, n0 = blockIdx.y * 128;
  const int lg = l >> 4, lm = l & 15;

  const int crow = tid >> 2;
  const int ck8 = (tid & 3) * 8;

  const float* Af = (const float*)Ap;
  const unsigned short* Ab = (const unsigned short*)Ap;

  f32x4 acc[4][4] = {};
  uint4 ra[2], rb[2];

  auto loadA = [&](int kt, int half) -> uint4 {
    const int row = crow + half * 64;
    const long off = (long)(m0 + row) * K + kt * 32 + ck8;
    if constexpr (AF32) {
      float4 f0 = *(const float4*)(Af + off);
      float4 f1 = *(const float4*)(Af + off + 4);
      bf16x8 v;
      v[0] = (__bf16)f0.x; v[1] = (__bf16)f0.y;
      v[2] = (__bf16)f0.z; v[3] = (__bf16)f0.w;
      v[4] = (__bf16)f1.x; v[5] = (__bf16)f1.y;
      v[6] = (__bf16)f1.z; v[7] = (__bf16)f1.w;
      uint4 u;
      __builtin_memcpy(&u, &v, 16);
      return u;
    } else {
      return *(const uint4*)(Ab + off);
    }
  };
  auto loadB = [&](int kt, int half) -> uint4 {
    const int row = crow + half * 64;
    return *(const uint4*)(W + (long)(n0 + row) * K + kt * 32 + ck8);
  };

  ra[0] = loadA(0, 0); ra[1] = loadA(0, 1);
  rb[0] = loadB(0, 0); rb[1] = loadB(0, 1);

  for (int kt = 0; kt < K / 32; ++kt) {
    __syncthreads();
    *(uint4*)&Alds[crow][ck8] = ra[0];
    *(uint4*)&Alds[crow + 64][ck8] = ra[1];
    *(uint4*)&Blds[crow][ck8] = rb[0];
    *(uint4*)&Blds[crow + 64][ck8] = rb[1];
    __syncthreads();
    if (kt + 1 < K / 32) {
      ra[0] = loadA(kt + 1, 0); ra[1] = loadA(kt + 1, 1);
      rb[0] = loadB(kt + 1, 0); rb[1] = loadB(kt + 1, 1);
    }
    bf16x8 af[4], bfr[4];
#pragma unroll
    for (int i = 0; i < 4; ++i)
      af[i] = *(const bf16x8*)&Alds[wr * 64 + i * 16 + lm][lg * 8];
#pragma unroll
    for (int j = 0; j < 4; ++j)
      bfr[j] = *(const bf16x8*)&Blds[wc * 64 + j * 16 + lm][lg * 8];
#pragma unroll
    for (int i = 0; i < 4; ++i)
#pragma unroll
      for (int j = 0; j < 4; ++j) {
        if constexpr (MODE == 1)
          acc[i][j] = mfma16(bfr[i], af[j], acc[i][j]);  // D^T = W * A^T
        else
          acc[i][j] = mfma16(af[i], bfr[j], acc[i][j]);
      }
  }

  const int rr = lg * 4;
  if constexpr (MODE == 0) {
    const int Lmask = (1 << Llog2) - 1;
    unsigned short* out = (unsigned short*)outp;
#pragma unroll
    for (int j = 0; j < 4; ++j) {
      const int n = n0 + wc * 64 + j * 16 + lm;
      const float bv = bias[n];
      const int h = n >> 6, d = n & 63;
#pragma unroll
      for (int i = 0; i < 4; ++i)
#pragma unroll
        for (int r = 0; r < 4; ++r) {
          const int m = m0 + wr * 64 + i * 16 + rr + r;
          const int b = m >> Llog2, li = m & Lmask;
          const long o = (((long)(b * 16 + h) << Llog2) + li) * 64 + d;
          out[o] = f2bf((acc[i][j][r] + bv) * oscale);
        }
    }
  } else if constexpr (MODE == 1) {
    unsigned short* out = (unsigned short*)outp;
#pragma unroll
    for (int i = 0; i < 4; ++i)
#pragma unroll
      for (int r = 0; r < 4; ++r) {
        const int n = n0 + wc * 64 + i * 16 + rr + r;
        const float bv = bias[n];
        const int h = n >> 6, d = n & 63;
#pragma unroll
        for (int j = 0; j < 4; ++j) {
          const int m = m0 + wr * 64 + j * 16 + lm;
          const int b = m >> 12, lk = m & 4095;
          const long o = ((long)((b * 16 + h) * 64 + d)) * 4096 + lk;
          out[o] = f2bf(acc[i][j][r] + bv);
        }
      }
  } else {
    float* out = (float*)outp;
#pragma unroll
    for (int j = 0; j < 4; ++j) {
      const int n = n0 + wc * 64 + j * 16 + lm;
      const float bv = bias[n];
#pragma unroll
      for (int i = 0; i < 4; ++i)
#pragma unroll
        for (int r = 0; r < 4; ++r) {
          const int m = m0 + wr * 64 + i * 16 + rr + r;
          out[(long)m * N + n] = acc[i][j][r] + bv;
        }
    }
  }
}

// ------------------------------ flash attention -----------------------------
// grid (bh=32, qb=8, sp=4); 256 thr = 4 waves, wave owns 32 q rows, 16 tiles.
// 32x32x16 mfma, swapped QK (lane owns one q-row), key rows bit2<->3 permuted
// so P stays in registers in PV B-fragment layout. Bias and l both via MFMA.
// qh [bh][1024][64] (pre-scaled 0.125*log2e), kh [bh][4096][64],
// vT [bh][64][4096], kb [b][4096] packed (bf16hi,bf16lo) of bias*log2e.
// Oh [sp][bh][1024][64] fp16 normalized, ml [sp][bh][1024][2] f32 (m, l)
__global__ __launch_bounds__(256, 3) void attn32(
    const unsigned short* __restrict__ qh, const unsigned short* __restrict__ kh,
    const unsigned short* __restrict__ vT, const unsigned* __restrict__ kb,
    unsigned short* __restrict__ Oh, float* __restrict__ ml) {
  __shared__ unsigned short Klds[2][64][64];
  __shared__ unsigned short Vlds[2][64][64];

  const int tid = threadIdx.x;
  const int wid = tid >> 6, lane = tid & 63;
  const int lq = lane & 31, hi = lane >> 5;
  const int bh = blockIdx.x, qb = blockIdx.y, sp = blockIdx.z;
  const int b = bh >> 4;
  const int q = qb * 128 + wid * 32 + lq;
  const int kt0 = sp * 16;                    // 16 tiles of 64 keys

  // Q fragments (B-operand: col=q, k = 8*hi + j within each 16-d block)
  bf16x8 qr[4];
  {
    const unsigned short* qp = qh + ((long)bh * 1024 + q) * 64 + hi * 8;
#pragma unroll
    for (int dc = 0; dc < 4; ++dc) qr[dc] = *(const bf16x8*)(qp + dc * 16);
  }

  // constant fragments
  union uv { uint4 u; bf16x8 v; };
  uv ones; ones.u = make_uint4(0x3F803F80u, 0x3F803F80u, 0x3F803F80u, 0x3F803F80u);
  uv bq;   bq.u = make_uint4(hi ? 0u : 0x3F803F80u, 0u, 0u, 0u);  // 1 at k=0,1

  // staging (global_load_lds): wave w fills rows 16w..16w+15 of K and V.
  // LDS linear (row, slot=lane&7); global source pre-swizzled slot^= row&7.
  // K rows hold key swap23(row) (bits 2<->3) for the P-layout trick.
  auto swap23 = [](int r) { return (r & 0x33) | ((r & 4) << 1) | ((r & 8) >> 1); };
  const int r0 = wid * 16 + (lane >> 3), r1 = r0 + 8;
  const int s0 = ((lane & 7) ^ (r0 & 7)) * 8;
  const int s1 = ((lane & 7) ^ (r1 & 7)) * 8;
  const unsigned short* kg0 =
      kh + ((long)bh * 4096 + kt0 * 64 + swap23(r0)) * 64 + s0;
  const unsigned short* kg1 =
      kh + ((long)bh * 4096 + kt0 * 64 + swap23(r1)) * 64 + s1;
  const unsigned short* vg0 = vT + ((long)bh * 64 + r0) * 4096 + kt0 * 64 + s0;
  const unsigned short* vg1 = vT + ((long)bh * 64 + r1) * 4096 + kt0 * 64 + s1;
  const unsigned* kbp = kb + b * 4096 + kt0 * 64;
  const int kbkey = swap23(lq);

  auto issue = [&](int t, int buf) {
    gload16(kg0 + (long)t * 4096, &Klds[buf][wid * 16][0]);
    gload16(kg1 + (long)t * 4096, &Klds[buf][wid * 16 + 8][0]);
    gload16(vg0 + t * 64, &Vlds[buf][wid * 16][0]);
    gload16(vg1 + t * 64, &Vlds[buf][wid * 16 + 8][0]);
  };
  issue(0, 0);

  const int rsw = lq & 7;
  float mreg = -1e30f;
  f32x16 oa0 = {}, oa1 = {}, lacc = {};

  for (int t = 0; t < 16; ++t) {
    const int buf = t & 1;
    __syncthreads();                      // drains own vmcnt; tile t visible
    if (t + 1 < 16) issue(t + 1, buf ^ 1);

    // bias pair for this wave's accumulator rows (keys permuted like K rows)
    const unsigned kbw0 = kbp[t * 64 + kbkey];
    const unsigned kbw1 = kbp[t * 64 + 32 + kbkey];

    // S^T = K' Q   (rows = permuted keys, cols = q)
    f32x16 sa0 = {}, sa1 = {};
    __builtin_amdgcn_s_setprio(1);
#pragma unroll
    for (int dc = 0; dc < 4; ++dc) {
      const int so = ((dc * 2 + hi) ^ rsw) * 8;
      bf16x8 kf0 = *(const bf16x8*)&Klds[buf][lq][so];
      bf16x8 kf1 = *(const bf16x8*)&Klds[buf][32 + lq][so];
      sa0 = mfma32(kf0, qr[dc], sa0);
      sa1 = mfma32(kf1, qr[dc], sa1);
    }
    {  // bias += via 5th k-block: A = (hi,lo) pair, B = {1,1,0...}
      uv ka0, ka1;
      ka0.u = make_uint4(hi ? 0u : kbw0, 0u, 0u, 0u);
      ka1.u = make_uint4(hi ? 0u : kbw1, 0u, 0u, 0u);
      sa0 = mfma32(ka0.v, bq.v, sa0);
      sa1 = mfma32(ka1.v, bq.v, sa1);
    }
    __builtin_amdgcn_s_setprio(0);

    float p[32];
#pragma unroll
    for (int r = 0; r < 16; ++r) { p[r] = sa0[r]; p[16 + r] = sa1[r]; }

    // tile max (lane owns one q-row; partner lane^32 has the other 32 keys)
    float t8[8];
#pragma unroll
    for (int i = 0; i < 8; ++i)
      t8[i] = fmaxf(fmaxf(p[i], p[i + 8]), fmaxf(p[i + 16], p[i + 24]));
    float mx = fmaxf(fmaxf(fmaxf(t8[0], t8[1]), fmaxf(t8[2], t8[3])),
                     fmaxf(fmaxf(t8[4], t8[5]), fmaxf(t8[6], t8[7])));
    mx = fmaxf(mx, __shfl_xor(mx, 32));

    // defer-max (T13): rescale only when max grew past threshold
    if (!__all(mx - mreg <= 8.0f)) {
      const float mnew = fmaxf(mreg, mx);
      const float al = __builtin_amdgcn_exp2f(mreg - mnew);
      mreg = mnew;
#pragma unroll
      for (int r = 0; r < 16; ++r) { oa0[r] *= al; oa1[r] *= al; }
      lacc[0] *= al;
    }
#pragma unroll
    for (int i = 0; i < 32; ++i) p[i] = __builtin_amdgcn_exp2f(p[i] - mreg);

    // PV + l-accumulation (P already in B-fragment layout)
    __builtin_amdgcn_s_setprio(1);
#pragma unroll
    for (int kc = 0; kc < 4; ++kc) {
      uv pu;
      pu.u = make_uint4(pk2(p[kc * 8 + 0], p[kc * 8 + 1]),
                        pk2(p[kc * 8 + 2], p[kc * 8 + 3]),
                        pk2(p[kc * 8 + 4], p[kc * 8 + 5]),
                        pk2(p[kc * 8 + 6], p[kc * 8 + 7]));
      const int so = ((kc * 2 + hi) ^ rsw) * 8;
      bf16x8 vf0 = *(const bf16x8*)&Vlds[buf][lq][so];
      bf16x8 vf1 = *(const bf16x8*)&Vlds[buf][32 + lq][so];
      oa0 = mfma32(vf0, pu.v, oa0);
      oa1 = mfma32(vf1, pu.v, oa1);
      lacc = mfma32(ones.v, pu.v, lacc);
    }
    __builtin_amdgcn_s_setprio(0);
  }

  // epilogue: normalized fp16 partial + (m, l)
  const float lsum = lacc[0];
  const float inv = 1.0f / lsum;
  unsigned short* ob = Oh + (((long)sp * 32 + bh) * 1024 + q) * 64 + hi * 4;
#pragma unroll
  for (int g = 0; g < 4; ++g) {
    ushort4 u0, u1;
    u0.x = f2h(oa0[g * 4 + 0] * inv); u0.y = f2h(oa0[g * 4 + 1] * inv);
    u0.z = f2h(oa0[g * 4 + 2] * inv); u0.w = f2h(oa0[g * 4 + 3] * inv);
    u1.x = f2h(oa1[g * 4 + 0] * inv); u1.y = f2h(oa1[g * 4 + 1] * inv);
    u1.z = f2h(oa1[g * 4 + 2] * inv); u1.w = f2h(oa1[g * 4 + 3] * inv);
    *(ushort4*)(ob + g * 8) = u0;
    *(ushort4*)(ob + 32 + g * 8) = u1;
  }
  if (hi == 0)
    *(float2*)(ml + (((long)sp * 32 + bh) * 1024 + q) * 2) =
        make_float2(mreg, lsum);
}

// ------------------------------ split-K combine -----------------------------
__global__ __launch_bounds__(256) void combine4(
    const unsigned short* __restrict__ Oh, const float* __restrict__ ml,
    unsigned short* __restrict__ ao) {
  const int idx = blockIdx.x * 256 + threadIdx.x;   // 0..32767 (bh*1024+q)
  const int bh = idx >> 10, q = idx & 1023;
  const int b = bh >> 4, h = bh & 15;
  float m[4], l[4];
#pragma unroll
  for (int i = 0; i < 4; ++i) {
    float2 t = *(const float2*)(ml + ((long)i * 32768 + idx) * 2);
    m[i] = t.x; l[i] = t.y;
  }
  const float mm = fmaxf(fmaxf(m[0], m[1]), fmaxf(m[2], m[3]));
  float w[4], wsum = 0.f;
#pragma unroll
  for (int i = 0; i < 4; ++i) {
    w[i] = l[i] * __builtin_amdgcn_exp2f(m[i] - mm);
    wsum += w[i];
  }
  const float inv = 1.0f / wsum;
#pragma unroll
  for (int i = 0; i < 4; ++i) w[i] *= inv;

  unsigned short* op = ao + ((long)b * 1024 + q) * 1024 + h * 64;
#pragma unroll
  for (int blk = 0; blk < 8; ++blk) {        // 8 d per block
    float acc[8] = {};
#pragma unroll
    for (int i = 0; i < 4; ++i) {
      uint4 u = *(const uint4*)(Oh + ((long)i * 32768 + idx) * 64 + blk * 8);
      const unsigned short* hs = (const unsigned short*)&u;
#pragma unroll
      for (int j = 0; j < 8; ++j) acc[j] += w[i] * h2f(hs[j]);
    }
    ushort4 o0, o1;
    o0.x = f2bf(acc[0]); o0.y = f2bf(acc[1]);
    o0.z = f2bf(acc[2]); o0.w = f2bf(acc[3]);
    o1.x = f2bf(acc[4]); o1.y = f2bf(acc[5]);
    o1.z = f2bf(acc[6]); o1.w = f2bf(acc[7]);
    *(ushort4*)(op + blk * 8) = o0;
    *(ushort4*)(op + blk * 8 + 4) = o1;
  }
}

// --------------------------------- launcher ---------------------------------
extern "C" void kernel_launch(void* const* d_in, const int* in_sizes, int n_in,
                              void* d_out, int out_size, void* d_ws,
                              size_t ws_size, hipStream_t stream) {
  const float* Q = (const float*)d_in[0];
  const float* K_in = (const float*)d_in[1];
  const float* V_in = (const float*)d_in[2];
  const float* V_bias = (const float*)d_in[3];
  const float* Wq_w = (const float*)d_in[4];
  const float* Wq_b = (const float*)d_in[5];
  const float* Wk_w = (const float*)d_in[6];
  const float* Wk_b = (const float*)d_in[7];
  const float* Wv_w = (const float*)d_in[8];
  const float* Wv_b = (const float*)d_in[9];
  const float* Wo_w = (const float*)d_in[10];
  const float* Wo_b = (const float*)d_in[11];

  char* ws = (char*)d_ws;  // 64.5 MB footprint (proven in R1/R2)
  unsigned short* Wqb = (unsigned short*)(ws + (0l << 20));
  float* mlp = (float*)(ws + (0l << 20));   // aliases Wqb (dead after Q-proj)
  unsigned short* Wkb = (unsigned short*)(ws + (2l << 20));
  unsigned short* Wvb = (unsigned short*)(ws + (4l << 20));
  unsigned short* Wob = (unsigned short*)(ws + (6l << 20));
  unsigned short* qhp = (unsigned short*)(ws + (8l << 20));   // 4 MB
  unsigned short* khp = (unsigned short*)(ws + (12l << 20));  // 16 MB
  unsigned short* vTp = (unsigned short*)(ws + (28l << 20));  // 16 MB
  unsigned short* Ohp = (unsigned short*)(ws + (44l << 20));  // 16 MB fp16
  unsigned short* aop = (unsigned short*)(ws + (60l << 20));  // 4 MB
  unsigned* kbp = (unsigned*)(ws + (64l << 20));              // 32 KB

  Cvt4 c4;
  c4.src[0] = Wq_w; c4.src[1] = Wk_w; c4.src[2] = Wv_w; c4.src[3] = Wo_w;
  c4.dst[0] = Wqb;  c4.dst[1] = Wkb;  c4.dst[2] = Wvb;  c4.dst[3] = Wob;
  cvt4_kernel<<<dim3(256, 4), 256, 0, stream>>>(c4, (1024 * 1024) / 4);
  prep_kb<<<32, 256, 0, stream>>>(V_bias, kbp);

  // Q pre-scaled by 1/sqrt(D) * log2(e) so attention works in exp2 domain
  gemm_bf16<0, true><<<dim3(16, 8), 256, 0, stream>>>(
      Q, Wqb, Wq_b, qhp, 2048, 10, 0.125f * LOG2E);
  gemm_bf16<0, true><<<dim3(64, 8), 256, 0, stream>>>(
      K_in, Wkb, Wk_b, khp, 8192, 12, 1.0f);
  gemm_bf16<1, true><<<dim3(64, 8), 256, 0, stream>>>(
      V_in, Wvb, Wv_b, vTp, 8192, 12, 1.0f);

  attn32<<<dim3(32, 8, 4), 256, 0, stream>>>(qhp, khp, vTp, kbp, Ohp, mlp);
  combine4<<<128, 256, 0, stream>>>(Ohp, mlp, aop);

  gemm_bf16<2, false><<<dim3(16, 8), 256, 0, stream>>>(
      aop, Wob, Wo_b, d_out, 2048, 0, 1.0f);
}